// Round 4
// baseline (4250.837 us; speedup 1.0000x reference)
//
#include <hip/hip_runtime.h>
#include <math.h>

#define NTS 12
#define NND 2048
#define NED 32768
#define XDI 128
#define HDI 256
#define H2I 512
#define ZDI 32
#define EPSC 1e-10f
#define NHC (NND * HDI)          // 524288  (h-plane elements)
#define ZPL (NND * 64)           // 131072  (zcat plane elements)
#define XSZ ((size_t)NTS * NND * XDI)

typedef unsigned short u16;
typedef __bf16 bf16x8 __attribute__((ext_vector_type(8)));
typedef float f32x4 __attribute__((ext_vector_type(4)));

// ---------------- device helpers ----------------

__device__ __forceinline__ float lsigf(float x) {
    return fminf(x, 0.f) - log1pf(expf(-fabsf(x)));
}

template <int ACT>
__device__ __forceinline__ float actf(float v) {
    if (ACT == 1) return fmaxf(v, 0.f);
    if (ACT == 2) return 1.f / (1.f + expf(-v));
    if (ACT == 3) return tanhf(v);
    if (ACT == 4) return fmaxf(v, 0.f) + log1pf(expf(-fabsf(v)));
    return v;
}

__device__ __forceinline__ u16 f2b(float f) {
    unsigned u = __float_as_uint(f);
    u += 0x7fffu + ((u >> 16) & 1u);   // RNE
    return (u16)(u >> 16);
}
__device__ __forceinline__ float b2f(u16 b) {
    return __uint_as_float((unsigned)b << 16);
}
__device__ __forceinline__ void f2b2(float v, u16& hi, u16& lo) {
    hi = f2b(v);
    lo = f2b(v - b2f(hi));
}

// ---------------- CSR build (all 12 timesteps upfront) ----------------

__global__ void count_all(const int* __restrict__ ei, int* __restrict__ counts) {
    int idx = blockIdx.x * 256 + threadIdx.x;
    int t = idx >> 15;
    int e = idx & (NED - 1);
    const int* dst = ei + (size_t)t * 2 * NED + NED;
    atomicAdd(&counts[t * NND + dst[e]], 1);
}

__global__ void scan_all(const int* __restrict__ counts, int* __restrict__ offsets,
                         float* __restrict__ deg, float* __restrict__ dinv) {
    int t = blockIdx.x;
    const int* cnt = counts + t * NND;
    int* off = offsets + t * (NND + 1);
    float* dg = deg + t * NND;
    float* dv = dinv + t * NND;
    __shared__ int tsum[256];
    int tid = threadIdx.x;
    int base = tid * 8;
    int local[8];
    int s = 0;
    for (int i = 0; i < 8; i++) { local[i] = s; s += cnt[base + i]; }
    tsum[tid] = s;
    __syncthreads();
    for (int offp = 1; offp < 256; offp <<= 1) {
        int v = (tid >= offp) ? tsum[tid - offp] : 0;
        __syncthreads();
        tsum[tid] += v;
        __syncthreads();
    }
    int excl = tsum[tid] - s;
    for (int i = 0; i < 8; i++) off[base + i] = excl + local[i];
    if (tid == 255) off[NND] = excl + s;
    for (int i = 0; i < 8; i++) {
        float d = (float)cnt[base + i] + 1.0f;
        dg[base + i] = d;
        dv[base + i] = 1.0f / sqrtf(d);
    }
}

__global__ void fill_all(const int* __restrict__ ei, const int* __restrict__ offsets,
                         int* __restrict__ cursor, const float* __restrict__ dinv,
                         int* __restrict__ csrc, float* __restrict__ csrw) {
    int idx = blockIdx.x * 256 + threadIdx.x;
    int t = idx >> 15;
    int e = idx & (NED - 1);
    const int* src = ei + (size_t)t * 2 * NED;
    const int* dst = src + NED;
    int d = dst[e], s = src[e];
    const int* off_t = offsets + t * (NND + 1);
    int pos = off_t[d] + atomicAdd(&cursor[t * NND + d], 1);
    csrc[(size_t)t * NED + pos] = s;
    csrw[(size_t)t * NED + pos] = dinv[t * NND + s] * dinv[t * NND + d];
}

// ---------------- weight convert+transpose: W[K,256] fp32 -> Wt hi/lo [256,K] bf16 ----------------
struct WtArgs {
    const float* W[18];
    u16* Wt[18];
    int K[18];
};

__global__ void wt_transpose(WtArgs a) {
    int m = blockIdx.y;
    int k = blockIdx.x;
    int K = a.K[m];
    if (k >= K) return;
    int c = threadIdx.x;
    float v = a.W[m][(size_t)k * HDI + c];
    u16 hi, lo;
    f2b2(v, hi, lo);
    a.Wt[m][(size_t)c * K + k] = hi;
    a.Wt[m][(size_t)K * HDI + (size_t)c * K + k] = lo;
}

// ---------------- x convert (hi/lo planes) ----------------
__global__ void cvt_x(const float* __restrict__ x, u16* __restrict__ xb) {
    size_t i = (size_t)blockIdx.x * 256 + threadIdx.x;  // over float4s
    float4 v = ((const float4*)x)[i];
    ushort4 h, l;
    f2b2(v.x, h.x, l.x); f2b2(v.y, h.y, l.y);
    f2b2(v.z, h.z, l.z); f2b2(v.w, h.w, l.w);
    ((ushort4*)xb)[i] = h;
    ((ushort4*)(xb + XSZ))[i] = l;
}

// ---------------- multi-segment GIN gather (fp32 in; fp32 or bf16 hi/lo out) ----------------
struct GatherArgs {
    const float* in[3];
    void* out[3];
    int ostr[3];
    int ooff[3];
    int obf[3];
    int plsz[3];   // bf16 plane size in elements
};

__global__ __launch_bounds__(256) void gather_multi(GatherArgs ga,
                                                    const int* __restrict__ offsets,
                                                    const int* __restrict__ csrc) {
    int seg = blockIdx.y;
    const float* in = ga.in[seg];
    void* outp = ga.out[seg];
    int ostr = ga.ostr[seg], ooff = ga.ooff[seg], obf = ga.obf[seg];
    int ln = threadIdx.x >> 6;
    int lane = threadIdx.x & 63;
    int n = blockIdx.x * 4 + ln;
    int e0 = offsets[n], e1 = offsets[n + 1];
    int c4 = lane * 4;
    float4 a = *(const float4*)&in[(size_t)n * HDI + c4];
    int j = e0;
    for (; j + 1 < e1; j += 2) {
        int s0 = csrc[j], s1 = csrc[j + 1];
        float4 v0 = *(const float4*)&in[(size_t)s0 * HDI + c4];
        float4 v1 = *(const float4*)&in[(size_t)s1 * HDI + c4];
        a.x += v0.x + v1.x; a.y += v0.y + v1.y; a.z += v0.z + v1.z; a.w += v0.w + v1.w;
    }
    if (j < e1) {
        int s0 = csrc[j];
        float4 v0 = *(const float4*)&in[(size_t)s0 * HDI + c4];
        a.x += v0.x; a.y += v0.y; a.z += v0.z; a.w += v0.w;
    }
    size_t oidx = (size_t)n * ostr + ooff + c4;
    if (obf) {
        ushort4 h, l;
        f2b2(a.x, h.x, l.x); f2b2(a.y, h.y, l.y);
        f2b2(a.z, h.z, l.z); f2b2(a.w, h.w, l.w);
        *(ushort4*)((u16*)outp + oidx) = h;
        *(ushort4*)((u16*)outp + ga.plsz[seg] + oidx) = l;
    } else {
        *(float4*)((float*)outp + oidx) = a;
    }
}

// ---------------- GCN pair ----------------
__global__ void gcn_pair(const float* __restrict__ xwA, const float* __restrict__ xwB,
                         const float* __restrict__ bias2, const int* __restrict__ offsets,
                         const int* __restrict__ csrc, const float* __restrict__ csrw,
                         const float* __restrict__ deg, float* __restrict__ oA,
                         float* __restrict__ oB) {
    int sel = blockIdx.y;
    const float* xw = sel ? xwB : xwA;
    const float* b = bias2 + sel * ZDI;
    float* out = sel ? oB : oA;
    int n = blockIdx.x * 8 + (threadIdx.x >> 5);
    int m = threadIdx.x & 31;
    int e0 = offsets[n], e1 = offsets[n + 1];
    float acc = 0.f;
    for (int j = e0; j < e1; j++) acc += csrw[j] * xw[(size_t)csrc[j] * ZDI + m];
    out[(size_t)n * ZDI + m] = acc + xw[(size_t)n * ZDI + m] / deg[n] + b[m];
}

// ---------------- MFMA big GEMM (split-bf16 hi/lo, no LDS, 1 wave/block, 64x16/wave) ----------------
// C[o] = epi(A1 @ B1t[o]^T (+ A2 @ B2t[o]^T) + bias[o]); 3-MFMA split per product.
struct BigArgsM {
    const u16* A1; const u16* A2;
    const u16* B1[2]; const u16* B2[2];
    const float* bias[2];
    float* C[2];
    u16* Cb;                 // bf16 hi/lo copy (EPI2 + WBF)
    const float* h; const float* zgp;
    int K1, K2;
    int apl1, apl2;          // A plane sizes (elements)
};

template <int ACT, bool HAS_A2, bool HAS_BIAS, int EPI, bool TWO, bool WBF>
__global__ __launch_bounds__(64) void gemm_mfma(BigArgsM g) {
    const int lane = threadIdx.x;
    const int bx = blockIdx.x;
    const int outSel = TWO ? (bx >> 4) : 0;
    const int c0 = (bx & 15) * 16;
    const int r0 = blockIdx.y * 64;
    const int lr = lane & 15;
    const int kg = (lane >> 4) * 8;

    f32x4 acc[4] = {};

    {
        const int K = g.K1;
        const u16* ap = g.A1 + (size_t)(r0 + lr) * K + kg;
        const u16* al_p = ap + g.apl1;
        const u16* bp = g.B1[outSel] + (size_t)(c0 + lr) * K + kg;
        const u16* bl_p = bp + (size_t)K * HDI;
        for (int k0 = 0; k0 < K; k0 += 32) {
            bf16x8 bh = *(const bf16x8*)(bp + k0);
            bf16x8 bl = *(const bf16x8*)(bl_p + k0);
#pragma unroll
            for (int rt = 0; rt < 4; rt++) {
                bf16x8 ah = *(const bf16x8*)(ap + (size_t)(16 * rt) * K + k0);
                bf16x8 al = *(const bf16x8*)(al_p + (size_t)(16 * rt) * K + k0);
                acc[rt] = __builtin_amdgcn_mfma_f32_16x16x32_bf16(ah, bh, acc[rt], 0, 0, 0);
                acc[rt] = __builtin_amdgcn_mfma_f32_16x16x32_bf16(al, bh, acc[rt], 0, 0, 0);
                acc[rt] = __builtin_amdgcn_mfma_f32_16x16x32_bf16(ah, bl, acc[rt], 0, 0, 0);
            }
        }
    }
    if (HAS_A2) {
        const int K = g.K2;
        const u16* ap = g.A2 + (size_t)(r0 + lr) * K + kg;
        const u16* al_p = ap + g.apl2;
        const u16* bp = g.B2[outSel] + (size_t)(c0 + lr) * K + kg;
        const u16* bl_p = bp + (size_t)K * HDI;
        for (int k0 = 0; k0 < K; k0 += 32) {
            bf16x8 bh = *(const bf16x8*)(bp + k0);
            bf16x8 bl = *(const bf16x8*)(bl_p + k0);
#pragma unroll
            for (int rt = 0; rt < 4; rt++) {
                bf16x8 ah = *(const bf16x8*)(ap + (size_t)(16 * rt) * K + k0);
                bf16x8 al = *(const bf16x8*)(al_p + (size_t)(16 * rt) * K + k0);
                acc[rt] = __builtin_amdgcn_mfma_f32_16x16x32_bf16(ah, bh, acc[rt], 0, 0, 0);
                acc[rt] = __builtin_amdgcn_mfma_f32_16x16x32_bf16(al, bh, acc[rt], 0, 0, 0);
                acc[rt] = __builtin_amdgcn_mfma_f32_16x16x32_bf16(ah, bl, acc[rt], 0, 0, 0);
            }
        }
    }

    const float* bias = HAS_BIAS ? g.bias[outSel] : nullptr;
    float* C = g.C[outSel];
    const int ccol = c0 + lr;
#pragma unroll
    for (int rt = 0; rt < 4; rt++) {
#pragma unroll
        for (int i = 0; i < 4; i++) {
            const int r = r0 + rt * 16 + ((lane >> 4) << 2) + i;
            const size_t idx = (size_t)r * HDI + ccol;
            float tv = acc[rt][i];
            if (HAS_BIAS) tv += bias[ccol];
            float res;
            if (EPI == 2) {
                float z = g.zgp[idx], hh = g.h[idx];
                res = z * hh + (1.f - z) * tanhf(tv);
            } else if (EPI == 1) {
                res = actf<ACT>(tv);
                if (outSel == 1) res *= g.h[idx];
            } else {
                res = actf<ACT>(tv);
            }
            C[idx] = res;
            if (WBF) {
                u16 hi, lo;
                f2b2(res, hi, lo);
                g.Cb[idx] = hi;
                g.Cb[NHC + idx] = lo;
            }
        }
    }
}

// ---------------- small GEMM batch (fp32): C = act(A[2048,256]@B[256,32] + bias) ----------------
struct SmallArgs {
    const float* A[4]; const float* B[4]; const float* bias[4];
    float* C[4]; int act[4];
};

__global__ __launch_bounds__(256) void small_gemm(SmallArgs s) {
    __shared__ float As[8][260];
    __shared__ float Bs[256 * 32];
    const int y = blockIdx.y;
    const float* A = s.A[y];
    const float* B = s.B[y];
    const float* bi = s.bias[y];
    float* C = s.C[y];
    const int act = s.act[y];
    const int tid = threadIdx.x;
    const int n0 = blockIdx.x * 8;
    for (int idx = tid; idx < 512; idx += 256) {
        int r = idx >> 6, c4 = (idx & 63) * 4;
        *(float4*)&As[r][c4] = *(const float4*)&A[(size_t)(n0 + r) * HDI + c4];
    }
    for (int idx = tid; idx < 2048; idx += 256)
        *(float4*)&Bs[idx * 4] = *(const float4*)&B[idx * 4];
    __syncthreads();
    const int r = tid >> 5, m = tid & 31;
    float acc = bi ? bi[m] : 0.f;
#pragma unroll 8
    for (int k = 0; k < 256; k++) acc += As[r][k] * Bs[k * 32 + m];
    if (act == 4) acc = fmaxf(acc, 0.f) + log1pf(expf(-fabsf(acc)));
    C[(size_t)(n0 + r) * ZDI + m] = acc;
}

// ---------------- z build + KLD fused (also writes bf16 hi/lo zcat) ----------------
__global__ void zkld_kernel(const float* __restrict__ ms, const float* __restrict__ ss,
                            const float* __restrict__ es, const float* __restrict__ md,
                            const float* __restrict__ sd, const float* __restrict__ ed,
                            const float* __restrict__ pms, const float* __restrict__ pss,
                            const float* __restrict__ pmd, const float* __restrict__ psd,
                            float* __restrict__ zcat, u16* __restrict__ zb,
                            double* __restrict__ kacc) {
    int i = blockIdx.x * 256 + threadIdx.x;
    int n = i >> 5, z = i & 31;
    float m1 = ms[i], s1v = ss[i];
    float n1 = md[i], t1v = sd[i];
    float zs = m1 + s1v * es[i];
    float zd = n1 + t1v * ed[i];
    zcat[(size_t)n * 64 + z] = zs;
    zcat[(size_t)n * 64 + 32 + z] = zd;
    u16 hi, lo;
    f2b2(zs, hi, lo);
    zb[(size_t)n * 64 + z] = hi;
    zb[ZPL + (size_t)n * 64 + z] = lo;
    f2b2(zd, hi, lo);
    zb[(size_t)n * 64 + 32 + z] = hi;
    zb[ZPL + (size_t)n * 64 + 32 + z] = lo;
    float v;
    {
        float a1 = s1v + EPSC, a2 = pss[i] + EPSC;
        float dm = m1 - pms[i];
        v = 2.f * (logf(a2) - logf(a1)) + (a1 * a1 + dm * dm) / (a2 * a2) - 1.f;
    }
    {
        float a1 = t1v + EPSC, a2 = psd[i] + EPSC;
        float dm = n1 - pmd[i];
        v += 2.f * (logf(a2) - logf(a1)) + (a1 * a1 + dm * dm) / (a2 * a2) - 1.f;
    }
    __shared__ float red[256];
    red[threadIdx.x] = v;
    __syncthreads();
    for (int o = 128; o > 0; o >>= 1) {
        if (threadIdx.x < o) red[threadIdx.x] += red[threadIdx.x + o];
        __syncthreads();
    }
    if (threadIdx.x == 0) atomicAdd(kacc, (double)red[0]);
}

// ---------------- dec = z_s @ z_d^T + store + BCE partials ----------------
__global__ __launch_bounds__(256) void dec_bce(const float* __restrict__ zcat,
                                               const float* __restrict__ adj,
                                               float* __restrict__ dec,
                                               double* __restrict__ acc3) {
    __shared__ float zsS[32][68];
    __shared__ float zdS[32][68];
    const int tid = threadIdx.x;
    const int tx = tid & 15, ty = tid >> 4;
    const int r0 = blockIdx.y * 64, c0 = blockIdx.x * 64;
    const int lrow = tid >> 2;
    const int lk = (tid & 3) * 8;

    float4 v0 = *(const float4*)&zcat[(size_t)(r0 + lrow) * 64 + lk];
    float4 v1 = *(const float4*)&zcat[(size_t)(r0 + lrow) * 64 + lk + 4];
    float4 w0 = *(const float4*)&zcat[(size_t)(c0 + lrow) * 64 + 32 + lk];
    float4 w1 = *(const float4*)&zcat[(size_t)(c0 + lrow) * 64 + 32 + lk + 4];
    zsS[lk + 0][lrow] = v0.x; zsS[lk + 1][lrow] = v0.y; zsS[lk + 2][lrow] = v0.z; zsS[lk + 3][lrow] = v0.w;
    zsS[lk + 4][lrow] = v1.x; zsS[lk + 5][lrow] = v1.y; zsS[lk + 6][lrow] = v1.z; zsS[lk + 7][lrow] = v1.w;
    zdS[lk + 0][lrow] = w0.x; zdS[lk + 1][lrow] = w0.y; zdS[lk + 2][lrow] = w0.z; zdS[lk + 3][lrow] = w0.w;
    zdS[lk + 4][lrow] = w1.x; zdS[lk + 5][lrow] = w1.y; zdS[lk + 6][lrow] = w1.z; zdS[lk + 7][lrow] = w1.w;
    __syncthreads();

    float acc[4][4] = {};
#pragma unroll
    for (int k = 0; k < 32; k++) {
        const float4 a4 = *(const float4*)&zsS[k][ty * 4];
        const float4 b4 = *(const float4*)&zdS[k][tx * 4];
        const float aa[4] = {a4.x, a4.y, a4.z, a4.w};
        const float bb[4] = {b4.x, b4.y, b4.z, b4.w};
#pragma unroll
        for (int i = 0; i < 4; i++)
#pragma unroll
            for (int j = 0; j < 4; j++) acc[i][j] += aa[i] * bb[j];
    }

    float asum = 0.f, s1 = 0.f, s2 = 0.f;
#pragma unroll
    for (int i = 0; i < 4; i++) {
        const int r = r0 + ty * 4 + i;
        const float4 av4 = *(const float4*)&adj[(size_t)r * NND + c0 + tx * 4];
        const float av[4] = {av4.x, av4.y, av4.z, av4.w};
        float* drow = &dec[(size_t)r * NND + c0 + tx * 4];
#pragma unroll
        for (int j = 0; j < 4; j++) {
            float d = acc[i][j];
            drow[j] = d;
            float a = av[j];
            asum += a;
            s1 += a * lsigf(d);
            s2 += (1.f - a) * lsigf(-d);
        }
    }
    __shared__ float redA[256], redB[256], redC[256];
    redA[tid] = asum; redB[tid] = s1; redC[tid] = s2;
    __syncthreads();
    for (int o = 128; o > 0; o >>= 1) {
        if (tid < o) {
            redA[tid] += redA[tid + o];
            redB[tid] += redB[tid + o];
            redC[tid] += redC[tid + o];
        }
        __syncthreads();
    }
    if (tid == 0) {
        atomicAdd(&acc3[0], (double)redA[0]);
        atomicAdd(&acc3[1], (double)redB[0]);
        atomicAdd(&acc3[2], (double)redC[0]);
    }
}

// ---------------- finalize ----------------
__global__ void finalize_kernel(const double* __restrict__ accd, float* __restrict__ out) {
    if (threadIdx.x == 0 && blockIdx.x == 0) {
        const double nn2 = (double)NND * (double)NND;
        out[0] = (float)(0.5 * accd[0] / nn2);
        double nll = 0.0;
        for (int t = 0; t < NTS; ++t) {
            double s = accd[1 + 3 * t];
            double S1 = accd[2 + 3 * t];
            double S2 = accd[3 + 3 * t];
            double posw = (nn2 - s) / s;
            double norm = nn2 / ((nn2 - s) * 2.0);
            nll += norm * (-posw * S1 - S2) / nn2;
        }
        out[1] = (float)nll;
    }
}

// ---------------- host ----------------

extern "C" void kernel_launch(void* const* d_in, const int* in_sizes, int n_in,
                              void* d_out, int out_size, void* d_ws, size_t ws_size,
                              hipStream_t stream) {
    (void)in_sizes; (void)n_in; (void)out_size; (void)ws_size;

    const float* x_all = (const float*)d_in[0];
    const int* ei_all = (const int*)d_in[1];
    const float* adj_all = (const float*)d_in[2];
    const float* eps_s_all = (const float*)d_in[3];
    const float* eps_d_all = (const float*)d_in[4];
    const float* phi_x_w = (const float*)d_in[5];
    const float* phi_z_w = (const float*)d_in[6];
    const float* gru_xw0 = (const float*)d_in[7];
    const float* gru_xw1 = (const float*)d_in[8];
    const float* gru_hw = (const float*)d_in[9];
    const float* enc_w = (const float*)d_in[10];
    const float* enc_b = (const float*)d_in[11];
    const float* mean_w = (const float*)d_in[12];
    const float* mean_b = (const float*)d_in[13];
    const float* std_w = (const float*)d_in[14];
    const float* std_b = (const float*)d_in[15];
    const float* pri_w = (const float*)d_in[16];
    const float* pri_b = (const float*)d_in[17];
    const float* pri_mw = (const float*)d_in[18];
    const float* pri_mb = (const float*)d_in[19];
    const float* pri_sw = (const float*)d_in[20];
    const float* pri_sb = (const float*)d_in[21];
    float* out = (float*)d_out;

    size_t off = 0;
    auto alloc = [&](size_t bytes) -> void* {
        void* p = (char*)d_ws + off;
        off = (off + bytes + 255) & ~(size_t)255;
        return p;
    };
    const size_t NH = (size_t)NND * HDI;
    const size_t NH2 = (size_t)NND * H2I;
    const size_t NZ = (size_t)NND * ZDI;

    float* hbase = (float*)alloc(4 * NH * 4);          // h0,h1,nh0,nh1 fp32
    u16* h1b = (u16*)alloc(NH * 4);                    // bf16 hi/lo h1 ping
    u16* nh1b = (u16*)alloc(NH * 4);                   // bf16 hi/lo h1 pong
    float* phi_x = (float*)alloc(NH * 4);
    float* phi_z = (float*)alloc(NH * 4);
    float* enc_s = (float*)alloc(NH * 4);
    float* enc_d = (float*)alloc(NH * 4);
    float* ginA = (float*)alloc(NH * 4);               // fp32 gathers (std path)
    float* ginB = (float*)alloc(NH * 4);
    float* zg = (float*)alloc(NH * 4);                 // also pri_s
    float* rg = (float*)alloc(NH * 4);                 // also pri_d
    float* htmp = (float*)alloc(NH * 4);
    u16* cat_b = (u16*)alloc(NH2 * 4);                 // bf16 hi/lo gathers (mfma A)
    u16* xpre_b = (u16*)alloc(NH2 * 4);
    u16* xpre1_b = (u16*)alloc(NH * 4);
    u16* ginA_b = (u16*)alloc(NH * 4);
    u16* ginB_b = (u16*)alloc(NH * 4);
    float* zcat = (float*)alloc((size_t)NND * 64 * 4);
    u16* zcat_b = (u16*)alloc((size_t)NND * 64 * 4);
    u16* xb = (u16*)alloc(XSZ * 4);
    float* xw_s = (float*)alloc(NZ * 4);
    float* xw_d = (float*)alloc(NZ * 4);
    float* mean_s = (float*)alloc(NZ * 4);
    float* mean_d = (float*)alloc(NZ * 4);
    float* std_s = (float*)alloc(NZ * 4);
    float* std_d = (float*)alloc(NZ * 4);
    float* pm_s = (float*)alloc(NZ * 4);
    float* ps_s = (float*)alloc(NZ * 4);
    float* pm_d = (float*)alloc(NZ * 4);
    float* ps_d = (float*)alloc(NZ * 4);
    float* deg = (float*)alloc((size_t)NTS * NND * 4);
    float* dinv = (float*)alloc((size_t)NTS * NND * 4);
    int* counts = (int*)alloc(2 * (size_t)NTS * NND * 4);
    int* cursor = counts + (size_t)NTS * NND;
    int* offsets = (int*)alloc((size_t)NTS * (NND + 1) * 4);
    int* csrc = (int*)alloc((size_t)NTS * NED * 4);
    float* csrw = (float*)alloc((size_t)NTS * NED * 4);
    double* accd = (double*)alloc((1 + 3 * NTS) * 8);

    // transposed bf16 hi/lo weights
    WtArgs wa;
    int wk[18] = {XDI, 64, H2I, H2I, HDI, HDI, H2I, H2I, H2I, HDI, HDI, HDI,
                  HDI, HDI, HDI, HDI, HDI, HDI};
    const float* wsrc[18] = {
        phi_x_w, phi_z_w,
        enc_w, enc_w + (size_t)H2I * HDI,
        pri_w, pri_w + (size_t)HDI * HDI,
        gru_xw0, gru_xw0 + (size_t)H2I * HDI, gru_xw0 + 2 * (size_t)H2I * HDI,
        gru_xw1, gru_xw1 + (size_t)HDI * HDI, gru_xw1 + 2 * (size_t)HDI * HDI,
        gru_hw, gru_hw + (size_t)HDI * HDI, gru_hw + 2 * (size_t)HDI * HDI,
        gru_hw + 3 * (size_t)HDI * HDI, gru_hw + 4 * (size_t)HDI * HDI,
        gru_hw + 5 * (size_t)HDI * HDI};
    u16* wt[18];
    for (int m = 0; m < 18; m++) {
        wt[m] = (u16*)alloc((size_t)wk[m] * HDI * 4);  // hi + lo planes
        wa.W[m] = wsrc[m];
        wa.Wt[m] = wt[m];
        wa.K[m] = wk[m];
    }

    float* h0 = hbase;
    float* h1 = hbase + NH;
    float* nh0 = hbase + 2 * NH;
    float* nh1 = hbase + 3 * NH;

    hipMemsetAsync(hbase, 0, 2 * NH * 4, stream);
    hipMemsetAsync(h1b, 0, NH * 4, stream);
    hipMemsetAsync(counts, 0, 2 * (size_t)NTS * NND * 4, stream);
    hipMemsetAsync(accd, 0, (1 + 3 * NTS) * 8, stream);

    count_all<<<NTS * NED / 256, 256, 0, stream>>>(ei_all, counts);
    scan_all<<<NTS, 256, 0, stream>>>(counts, offsets, deg, dinv);
    fill_all<<<NTS * NED / 256, 256, 0, stream>>>(ei_all, offsets, cursor, dinv, csrc, csrw);
    wt_transpose<<<dim3(512, 18), 256, 0, stream>>>(wa);
    cvt_x<<<(int)(XSZ / 4 / 256), 256, 0, stream>>>(x_all, xb);

    const dim3 g1(16, 32);   // single-output mfma gemm
    const dim3 g2(32, 32);   // dual-output
    const dim3 gGather1(512, 1), gGather2(512, 2), gGather3(512, 3);

    for (int t = 0; t < NTS; ++t) {
        const float* adj_t = adj_all + (size_t)t * NND * NND;
        const float* es_t = eps_s_all + (size_t)t * NND * ZDI;
        const float* ed_t = eps_d_all + (size_t)t * NND * ZDI;
        float* dec_t = out + 2 + (size_t)t * NND * NND;
        const int* off_t = offsets + (size_t)t * (NND + 1);
        const int* csrc_t = csrc + (size_t)t * NED;
        const float* csrw_t = csrw + (size_t)t * NED;
        const float* deg_t = deg + (size_t)t * NND;

        BigArgsM ba;

        // phi_x = relu(x @ phi_x_w)
        ba = {}; ba.A1 = xb + (size_t)t * NND * XDI; ba.K1 = XDI; ba.apl1 = (int)XSZ;
        ba.B1[0] = wt[0]; ba.C[0] = phi_x;
        gemm_mfma<1, false, false, 0, false, false><<<g1, 64, 0, stream>>>(ba);

        // cat_b = gin([phi_x, h1]) -> bf16 hi/lo
        {
            GatherArgs ga = {};
            ga.in[0] = phi_x; ga.out[0] = cat_b; ga.ostr[0] = H2I; ga.ooff[0] = 0;   ga.obf[0] = 1; ga.plsz[0] = (int)NH2;
            ga.in[1] = h1;    ga.out[1] = cat_b; ga.ostr[1] = H2I; ga.ooff[1] = HDI; ga.obf[1] = 1; ga.plsz[1] = (int)NH2;
            gather_multi<<<gGather2, 256, 0, stream>>>(ga, off_t, csrc_t);
        }

        // enc_s / enc_d
        ba = {}; ba.A1 = cat_b; ba.K1 = H2I; ba.apl1 = (int)NH2;
        ba.B1[0] = wt[2]; ba.B1[1] = wt[3];
        ba.bias[0] = enc_b; ba.bias[1] = enc_b + HDI;
        ba.C[0] = enc_s; ba.C[1] = enc_d;
        gemm_mfma<1, false, true, 0, true, false><<<g2, 64, 0, stream>>>(ba);

        // xw_s / xw_d
        {
            SmallArgs sa = {};
            sa.A[0] = enc_s; sa.B[0] = mean_w; sa.C[0] = xw_s; sa.act[0] = 0;
            sa.A[1] = enc_d; sa.B[1] = mean_w + (size_t)HDI * ZDI; sa.C[1] = xw_d; sa.act[1] = 0;
            small_gemm<<<dim3(256, 2), 256, 0, stream>>>(sa);
        }
        gcn_pair<<<dim3(256, 2), 256, 0, stream>>>(xw_s, xw_d, mean_b, off_t, csrc_t, csrw_t,
                                                   deg_t, mean_s, mean_d);
        // gin(enc_s)->ginA fp32, gin(enc_d)->ginB fp32
        {
            GatherArgs ga = {};
            ga.in[0] = enc_s; ga.out[0] = ginA; ga.ostr[0] = HDI; ga.ooff[0] = 0; ga.obf[0] = 0;
            ga.in[1] = enc_d; ga.out[1] = ginB; ga.ostr[1] = HDI; ga.ooff[1] = 0; ga.obf[1] = 0;
            gather_multi<<<gGather2, 256, 0, stream>>>(ga, off_t, csrc_t);
        }
        // std_s / std_d
        {
            SmallArgs sa = {};
            sa.A[0] = ginA; sa.B[0] = std_w; sa.bias[0] = std_b; sa.C[0] = std_s; sa.act[0] = 4;
            sa.A[1] = ginB; sa.B[1] = std_w + (size_t)HDI * ZDI; sa.bias[1] = std_b + ZDI;
            sa.C[1] = std_d; sa.act[1] = 4;
            small_gemm<<<dim3(256, 2), 256, 0, stream>>>(sa);
        }

        // priors from h1 (bf16 hi/lo)
        ba = {}; ba.A1 = h1b; ba.K1 = HDI; ba.apl1 = (int)NH;
        ba.B1[0] = wt[4]; ba.B1[1] = wt[5];
        ba.bias[0] = pri_b; ba.bias[1] = pri_b + HDI;
        ba.C[0] = zg; ba.C[1] = rg;
        gemm_mfma<1, false, true, 0, true, false><<<g2, 64, 0, stream>>>(ba);

        {
            SmallArgs sa = {};
            sa.A[0] = zg; sa.B[0] = pri_mw; sa.bias[0] = pri_mb; sa.C[0] = pm_s; sa.act[0] = 0;
            sa.A[1] = zg; sa.B[1] = pri_sw; sa.bias[1] = pri_sb; sa.C[1] = ps_s; sa.act[1] = 4;
            sa.A[2] = rg; sa.B[2] = pri_mw + (size_t)HDI * ZDI; sa.bias[2] = pri_mb + ZDI;
            sa.C[2] = pm_d; sa.act[2] = 0;
            sa.A[3] = rg; sa.B[3] = pri_sw + (size_t)HDI * ZDI; sa.bias[3] = pri_sb + ZDI;
            sa.C[3] = ps_d; sa.act[3] = 4;
            small_gemm<<<dim3(256, 4), 256, 0, stream>>>(sa);
        }

        zkld_kernel<<<(int)(NZ / 256), 256, 0, stream>>>(mean_s, std_s, es_t, mean_d, std_d,
                                                         ed_t, pm_s, ps_s, pm_d, ps_d, zcat,
                                                         zcat_b, &accd[0]);
        // phi_z = relu(zcat @ phi_z_w)
        ba = {}; ba.A1 = zcat_b; ba.K1 = 64; ba.apl1 = ZPL;
        ba.B1[0] = wt[1]; ba.C[0] = phi_z;
        gemm_mfma<1, false, false, 0, false, false><<<g1, 64, 0, stream>>>(ba);
        dec_bce<<<dim3(NND / 64, NND / 64), 256, 0, stream>>>(zcat, adj_t, dec_t,
                                                              &accd[1 + 3 * t]);

        // xpre = gin([phi_x, phi_z]) bf16; ginA_b = gin(h0) bf16
        {
            GatherArgs ga = {};
            ga.in[0] = phi_x; ga.out[0] = xpre_b; ga.ostr[0] = H2I; ga.ooff[0] = 0;   ga.obf[0] = 1; ga.plsz[0] = (int)NH2;
            ga.in[1] = phi_z; ga.out[1] = xpre_b; ga.ostr[1] = H2I; ga.ooff[1] = HDI; ga.obf[1] = 1; ga.plsz[1] = (int)NH2;
            ga.in[2] = h0;    ga.out[2] = ginA_b; ga.ostr[2] = HDI; ga.ooff[2] = 0;   ga.obf[2] = 1; ga.plsz[2] = (int)NH;
            gather_multi<<<gGather3, 256, 0, stream>>>(ga, off_t, csrc_t);
        }

        // GRU L0 z/r: zg = sigmoid(...), htmp = sigmoid(...)*h0
        ba = {}; ba.A1 = xpre_b; ba.K1 = H2I; ba.apl1 = (int)NH2;
        ba.A2 = ginA_b; ba.K2 = HDI; ba.apl2 = (int)NH;
        ba.B1[0] = wt[6]; ba.B1[1] = wt[7];
        ba.B2[0] = wt[12]; ba.B2[1] = wt[13];
        ba.C[0] = zg; ba.C[1] = htmp; ba.h = h0;
        gemm_mfma<2, true, false, 1, true, false><<<g2, 64, 0, stream>>>(ba);
        {
            GatherArgs ga = {};
            ga.in[0] = htmp; ga.out[0] = ginB_b; ga.ostr[0] = HDI; ga.ooff[0] = 0; ga.obf[0] = 1; ga.plsz[0] = (int)NH;
            gather_multi<<<gGather1, 256, 0, stream>>>(ga, off_t, csrc_t);
        }
        // nh0 = zg*h0 + (1-zg)*tanh(...)
        ba = {}; ba.A1 = xpre_b; ba.K1 = H2I; ba.apl1 = (int)NH2;
        ba.A2 = ginB_b; ba.K2 = HDI; ba.apl2 = (int)NH;
        ba.B1[0] = wt[8]; ba.B2[0] = wt[14];
        ba.C[0] = nh0; ba.h = h0; ba.zgp = zg;
        gemm_mfma<0, true, false, 2, false, false><<<g1, 64, 0, stream>>>(ba);

        // xpre1 = gin(nh0) bf16; ginA_b = gin(h1) bf16
        {
            GatherArgs ga = {};
            ga.in[0] = nh0; ga.out[0] = xpre1_b; ga.ostr[0] = HDI; ga.ooff[0] = 0; ga.obf[0] = 1; ga.plsz[0] = (int)NH;
            ga.in[1] = h1;  ga.out[1] = ginA_b;  ga.ostr[1] = HDI; ga.ooff[1] = 0; ga.obf[1] = 1; ga.plsz[1] = (int)NH;
            gather_multi<<<gGather2, 256, 0, stream>>>(ga, off_t, csrc_t);
        }

        // GRU L1 z/r
        ba = {}; ba.A1 = xpre1_b; ba.K1 = HDI; ba.apl1 = (int)NH;
        ba.A2 = ginA_b; ba.K2 = HDI; ba.apl2 = (int)NH;
        ba.B1[0] = wt[9]; ba.B1[1] = wt[10];
        ba.B2[0] = wt[15]; ba.B2[1] = wt[16];
        ba.C[0] = zg; ba.C[1] = htmp; ba.h = h1;
        gemm_mfma<2, true, false, 1, true, false><<<g2, 64, 0, stream>>>(ba);
        {
            GatherArgs ga = {};
            ga.in[0] = htmp; ga.out[0] = ginB_b; ga.ostr[0] = HDI; ga.ooff[0] = 0; ga.obf[0] = 1; ga.plsz[0] = (int)NH;
            gather_multi<<<gGather1, 256, 0, stream>>>(ga, off_t, csrc_t);
        }
        // nh1 (+ bf16 hi/lo copy for next-step priors)
        ba = {}; ba.A1 = xpre1_b; ba.K1 = HDI; ba.apl1 = (int)NH;
        ba.A2 = ginB_b; ba.K2 = HDI; ba.apl2 = (int)NH;
        ba.B1[0] = wt[11]; ba.B2[0] = wt[17];
        ba.C[0] = nh1; ba.Cb = nh1b; ba.h = h1; ba.zgp = zg;
        gemm_mfma<0, true, false, 2, false, true><<<g1, 64, 0, stream>>>(ba);

        // swap ping-pong
        float* tp;
        tp = h0; h0 = nh0; nh0 = tp;
        tp = h1; h1 = nh1; nh1 = tp;
        u16* tb = h1b; h1b = nh1b; nh1b = tb;
    }

    finalize_kernel<<<1, 64, 0, stream>>>(accd, out);
}

// Round 5
// 4239.589 us; speedup vs baseline: 1.0027x; 1.0027x over previous
//
#include <hip/hip_runtime.h>
#include <math.h>

#define NTS 12
#define NND 2048
#define NED 32768
#define XDI 128
#define HDI 256
#define H2I 512
#define ZDI 32
#define EPSC 1e-10f
#define NHC (NND * HDI)          // 524288  (h-plane elements)
#define ZPL (NND * 64)           // 131072  (zcat plane elements)
#define XSZ ((size_t)NTS * NND * XDI)

typedef unsigned short u16;
typedef __bf16 bf16x8 __attribute__((ext_vector_type(8)));
typedef float f32x4 __attribute__((ext_vector_type(4)));

// ---------------- device helpers ----------------

__device__ __forceinline__ float lsigf(float x) {
    return fminf(x, 0.f) - log1pf(expf(-fabsf(x)));
}

__device__ __forceinline__ float actr(int a, float v) {
    if (a == 1) return fmaxf(v, 0.f);
    if (a == 2) return 1.f / (1.f + expf(-v));
    if (a == 3) return tanhf(v);
    if (a == 4) return fmaxf(v, 0.f) + log1pf(expf(-fabsf(v)));
    return v;
}

__device__ __forceinline__ u16 f2b(float f) {
    unsigned u = __float_as_uint(f);
    u += 0x7fffu + ((u >> 16) & 1u);   // RNE
    return (u16)(u >> 16);
}
__device__ __forceinline__ float b2f(u16 b) {
    return __uint_as_float((unsigned)b << 16);
}
__device__ __forceinline__ void f2b2(float v, u16& hi, u16& lo) {
    hi = f2b(v);
    lo = f2b(v - b2f(hi));
}

// ---------------- CSR build (all 12 timesteps upfront) ----------------

__global__ void count_all(const int* __restrict__ ei, int* __restrict__ counts) {
    int idx = blockIdx.x * 256 + threadIdx.x;
    int t = idx >> 15;
    int e = idx & (NED - 1);
    const int* dst = ei + (size_t)t * 2 * NED + NED;
    atomicAdd(&counts[t * NND + dst[e]], 1);
}

__global__ void scan_all(const int* __restrict__ counts, int* __restrict__ offsets,
                         float* __restrict__ deg, float* __restrict__ dinv) {
    int t = blockIdx.x;
    const int* cnt = counts + t * NND;
    int* off = offsets + t * (NND + 1);
    float* dg = deg + t * NND;
    float* dv = dinv + t * NND;
    __shared__ int tsum[256];
    int tid = threadIdx.x;
    int base = tid * 8;
    int local[8];
    int s = 0;
    for (int i = 0; i < 8; i++) { local[i] = s; s += cnt[base + i]; }
    tsum[tid] = s;
    __syncthreads();
    for (int offp = 1; offp < 256; offp <<= 1) {
        int v = (tid >= offp) ? tsum[tid - offp] : 0;
        __syncthreads();
        tsum[tid] += v;
        __syncthreads();
    }
    int excl = tsum[tid] - s;
    for (int i = 0; i < 8; i++) off[base + i] = excl + local[i];
    if (tid == 255) off[NND] = excl + s;
    for (int i = 0; i < 8; i++) {
        float d = (float)cnt[base + i] + 1.0f;
        dg[base + i] = d;
        dv[base + i] = 1.0f / sqrtf(d);
    }
}

__global__ void fill_all(const int* __restrict__ ei, const int* __restrict__ offsets,
                         int* __restrict__ cursor, const float* __restrict__ dinv,
                         int* __restrict__ csrc, float* __restrict__ csrw) {
    int idx = blockIdx.x * 256 + threadIdx.x;
    int t = idx >> 15;
    int e = idx & (NED - 1);
    const int* src = ei + (size_t)t * 2 * NED;
    const int* dst = src + NED;
    int d = dst[e], s = src[e];
    const int* off_t = offsets + t * (NND + 1);
    int pos = off_t[d] + atomicAdd(&cursor[t * NND + d], 1);
    csrc[(size_t)t * NED + pos] = s;
    csrw[(size_t)t * NED + pos] = dinv[t * NND + s] * dinv[t * NND + d];
}

// ---------------- weight convert+transpose: W[K,256] fp32 -> Wt hi/lo [256,K] bf16 ----------------
struct WtArgs {
    const float* W[18];
    u16* Wt[18];
    int K[18];
};

__global__ void wt_transpose(WtArgs a) {
    int m = blockIdx.y;
    int k = blockIdx.x;
    int K = a.K[m];
    if (k >= K) return;
    int c = threadIdx.x;
    float v = a.W[m][(size_t)k * HDI + c];
    u16 hi, lo;
    f2b2(v, hi, lo);
    a.Wt[m][(size_t)c * K + k] = hi;
    a.Wt[m][(size_t)K * HDI + (size_t)c * K + k] = lo;
}

// ---------------- x convert (hi/lo planes) ----------------
__global__ void cvt_x(const float* __restrict__ x, u16* __restrict__ xb) {
    size_t i = (size_t)blockIdx.x * 256 + threadIdx.x;  // over float4s
    float4 v = ((const float4*)x)[i];
    ushort4 h, l;
    f2b2(v.x, h.x, l.x); f2b2(v.y, h.y, l.y);
    f2b2(v.z, h.z, l.z); f2b2(v.w, h.w, l.w);
    ((ushort4*)xb)[i] = h;
    ((ushort4*)(xb + XSZ))[i] = l;
}

// ================= universal fat kernel =================
// Op type: 0 GEMM, 1 GATHER, 2 SMALL, 3 GCN, 4 ZKLD, 5 DEC
// GEMM   : a=A1 b=A2 c=B1[0] d=B1[1] e=B2[0] f=B2[1] g=bias0 h=bias1 i=hgate j=zgate
//          o0=C0 o1=C1 o2=Cb k1=K1 k2=K2 p1=apl1 p2=apl2 act epi flags(1=two,2=bias,4=a2,8=wbf)
// GATHER : a=in o0=out k1=ostr k2=ooff p1=obf p2=plane
// SMALL  : a=A b=B c=bias o0=C act
// GCN    : a=xw c=bias o0=out  (offs/csrc/csrw/deg from FatArgs)
// ZKLD   : a..j = ms,ss,es,md,sd,ed,pms,pss,pmd,psd  o0=zcat o1=zb o2=kacc
// DEC    : a=zcat b=adj o0=dec o1=acc3
struct Op {
    int type;
    const void *a, *b, *c, *d, *e, *f, *g, *h, *i, *j;
    void *o0, *o1, *o2;
    int k1, k2, p1, p2, act, epi, flags;
};

#define MAXOP 8
struct FatArgs {
    int nops;
    int blk_end[MAXOP];
    const int* offs;
    const int* csrcp;
    const float* csrwp;
    const float* degp;
    Op op[MAXOP];
};

__device__ void op_gemm(const Op& op, int lb, int tid) {
    const int wid = tid >> 6, lane = tid & 63;
    int w = lb * 4 + wid;
    int o = 0;
    if ((op.flags & 1) && w >= 2048) { o = 1; w -= 2048; }
    const int r = w & 127;        // 128 row tiles (M=2048)
    const int cc = w >> 7;        // 16 col tiles (N=256)
    const int lr = lane & 15, kg = (lane >> 4) * 8;
    f32x4 ac0 = {}, ac1 = {}, ac2 = {};
    const u16* A = (const u16*)op.a;
    const u16* B = (const u16*)(o ? op.d : op.c);
    int K = op.k1, apl = op.p1;
    for (int pass = 0;; pass++) {
        const u16* ap = A + (size_t)(r * 16 + lr) * K + kg;
        const u16* bp = B + (size_t)(cc * 16 + lr) * K + kg;
        const u16* alp = ap + apl;
        const u16* blp = bp + (size_t)K * HDI;
#pragma unroll 2
        for (int k0 = 0; k0 < K; k0 += 32) {
            bf16x8 ah = *(const bf16x8*)(ap + k0);
            bf16x8 al = *(const bf16x8*)(alp + k0);
            bf16x8 bh = *(const bf16x8*)(bp + k0);
            bf16x8 bl = *(const bf16x8*)(blp + k0);
            ac0 = __builtin_amdgcn_mfma_f32_16x16x32_bf16(ah, bh, ac0, 0, 0, 0);
            ac1 = __builtin_amdgcn_mfma_f32_16x16x32_bf16(al, bh, ac1, 0, 0, 0);
            ac2 = __builtin_amdgcn_mfma_f32_16x16x32_bf16(ah, bl, ac2, 0, 0, 0);
        }
        if (!(op.flags & 4) || pass) break;
        A = (const u16*)op.b;
        B = (const u16*)(o ? op.f : op.e);
        K = op.k2; apl = op.p2;
    }
    const float* bias = (const float*)(o ? op.h : op.g);
    float* C = (float*)(o ? op.o1 : op.o0);
    const int ccol = cc * 16 + lr;
    const int rbase = r * 16 + (lane >> 4) * 4;
#pragma unroll
    for (int ii = 0; ii < 4; ii++) {
        size_t idx = (size_t)(rbase + ii) * HDI + ccol;
        float tv = ac0[ii] + ac1[ii] + ac2[ii];
        if (op.flags & 2) tv += bias[ccol];
        float res;
        if (op.epi == 2) {
            float z = ((const float*)op.j)[idx], hh = ((const float*)op.i)[idx];
            res = z * hh + (1.f - z) * tanhf(tv);
        } else if (op.epi == 1) {
            res = actr(op.act, tv);
            if (o) res *= ((const float*)op.i)[idx];
        } else {
            res = actr(op.act, tv);
        }
        C[idx] = res;
        if (op.flags & 8) {
            u16 hi, lo;
            f2b2(res, hi, lo);
            ((u16*)op.o2)[idx] = hi;
            ((u16*)op.o2)[NHC + idx] = lo;
        }
    }
}

__device__ void op_gather(const Op& op, const FatArgs& fa, int lb, int tid) {
    const float* in = (const float*)op.a;
    int ln = tid >> 6;
    int lane = tid & 63;
    int n = lb * 4 + ln;
    int e0 = fa.offs[n], e1 = fa.offs[n + 1];
    int c4 = lane * 4;
    float4 a = *(const float4*)&in[(size_t)n * HDI + c4];
    int j = e0;
    for (; j + 1 < e1; j += 2) {
        int s0 = fa.csrcp[j], s1 = fa.csrcp[j + 1];
        float4 v0 = *(const float4*)&in[(size_t)s0 * HDI + c4];
        float4 v1 = *(const float4*)&in[(size_t)s1 * HDI + c4];
        a.x += v0.x + v1.x; a.y += v0.y + v1.y; a.z += v0.z + v1.z; a.w += v0.w + v1.w;
    }
    if (j < e1) {
        int s0 = fa.csrcp[j];
        float4 v0 = *(const float4*)&in[(size_t)s0 * HDI + c4];
        a.x += v0.x; a.y += v0.y; a.z += v0.z; a.w += v0.w;
    }
    size_t oidx = (size_t)n * op.k1 + op.k2 + c4;
    if (op.p1) {
        ushort4 h, l;
        f2b2(a.x, h.x, l.x); f2b2(a.y, h.y, l.y);
        f2b2(a.z, h.z, l.z); f2b2(a.w, h.w, l.w);
        *(ushort4*)((u16*)op.o0 + oidx) = h;
        *(ushort4*)((u16*)op.o0 + op.p2 + oidx) = l;
    } else {
        *(float4*)((float*)op.o0 + oidx) = a;
    }
}

__device__ void op_small(const Op& op, int lb, int tid) {
    const int wid = tid >> 6, lane = tid & 63;
    const int n = lb * 8 + wid * 2 + (lane >> 5);
    const int m = lane & 31;
    const float* A = (const float*)op.a;
    const float* B = (const float*)op.b;
    const float* bi = (const float*)op.c;
    float acc = bi ? bi[m] : 0.f;
    const float* ar = A + (size_t)n * HDI;
#pragma unroll 4
    for (int k = 0; k < 256; k += 4) {
        float4 a4 = *(const float4*)(ar + k);
        acc += a4.x * B[(k + 0) * 32 + m];
        acc += a4.y * B[(k + 1) * 32 + m];
        acc += a4.z * B[(k + 2) * 32 + m];
        acc += a4.w * B[(k + 3) * 32 + m];
    }
    if (op.act == 4) acc = fmaxf(acc, 0.f) + log1pf(expf(-fabsf(acc)));
    ((float*)op.o0)[(size_t)n * ZDI + m] = acc;
}

__device__ void op_gcn(const Op& op, const FatArgs& fa, int lb, int tid) {
    int n = lb * 8 + (tid >> 5);
    int m = tid & 31;
    const float* xw = (const float*)op.a;
    const float* b = (const float*)op.c;
    int e0 = fa.offs[n], e1 = fa.offs[n + 1];
    float acc = 0.f;
    for (int j = e0; j < e1; j++) acc += fa.csrwp[j] * xw[(size_t)fa.csrcp[j] * ZDI + m];
    ((float*)op.o0)[(size_t)n * ZDI + m] =
        acc + xw[(size_t)n * ZDI + m] / fa.degp[n] + b[m];
}

__device__ void op_zkld(const Op& op, int lb, int tid) {
    int i = lb * 256 + tid;
    int n = i >> 5, z = i & 31;
    float m1 = ((const float*)op.a)[i], s1v = ((const float*)op.b)[i];
    float n1 = ((const float*)op.d)[i], t1v = ((const float*)op.e)[i];
    float zs = m1 + s1v * ((const float*)op.c)[i];
    float zd = n1 + t1v * ((const float*)op.f)[i];
    float* zcat = (float*)op.o0;
    u16* zb = (u16*)op.o1;
    zcat[(size_t)n * 64 + z] = zs;
    zcat[(size_t)n * 64 + 32 + z] = zd;
    u16 hi, lo;
    f2b2(zs, hi, lo);
    zb[(size_t)n * 64 + z] = hi;
    zb[ZPL + (size_t)n * 64 + z] = lo;
    f2b2(zd, hi, lo);
    zb[(size_t)n * 64 + 32 + z] = hi;
    zb[ZPL + (size_t)n * 64 + 32 + z] = lo;
    float v;
    {
        float a1 = s1v + EPSC, a2 = ((const float*)op.h)[i] + EPSC;
        float dm = m1 - ((const float*)op.g)[i];
        v = 2.f * (logf(a2) - logf(a1)) + (a1 * a1 + dm * dm) / (a2 * a2) - 1.f;
    }
    {
        float a1 = t1v + EPSC, a2 = ((const float*)op.j)[i] + EPSC;
        float dm = n1 - ((const float*)op.i)[i];
        v += 2.f * (logf(a2) - logf(a1)) + (a1 * a1 + dm * dm) / (a2 * a2) - 1.f;
    }
#pragma unroll
    for (int o = 32; o > 0; o >>= 1) v += __shfl_down(v, o);
    if ((tid & 63) == 0) atomicAdd((double*)op.o2, (double)v);
}

__device__ void op_dec(const Op& op, int lb, int tid, char* smem) {
    const float* zcat = (const float*)op.a;
    const float* adj = (const float*)op.b;
    float* dec = (float*)op.o0;
    double* acc3 = (double*)op.o1;
    float (*zsS)[68] = (float(*)[68])smem;
    float (*zdS)[68] = (float(*)[68])(smem + 32 * 68 * 4);
    const int tx = tid & 15, ty = tid >> 4;
    const int c0 = (lb & 31) * 64, r0 = (lb >> 5) * 64;
    const int lrow = tid >> 2;
    const int lk = (tid & 3) * 8;

    float4 v0 = *(const float4*)&zcat[(size_t)(r0 + lrow) * 64 + lk];
    float4 v1 = *(const float4*)&zcat[(size_t)(r0 + lrow) * 64 + lk + 4];
    float4 w0 = *(const float4*)&zcat[(size_t)(c0 + lrow) * 64 + 32 + lk];
    float4 w1 = *(const float4*)&zcat[(size_t)(c0 + lrow) * 64 + 32 + lk + 4];
    zsS[lk + 0][lrow] = v0.x; zsS[lk + 1][lrow] = v0.y; zsS[lk + 2][lrow] = v0.z; zsS[lk + 3][lrow] = v0.w;
    zsS[lk + 4][lrow] = v1.x; zsS[lk + 5][lrow] = v1.y; zsS[lk + 6][lrow] = v1.z; zsS[lk + 7][lrow] = v1.w;
    zdS[lk + 0][lrow] = w0.x; zdS[lk + 1][lrow] = w0.y; zdS[lk + 2][lrow] = w0.z; zdS[lk + 3][lrow] = w0.w;
    zdS[lk + 4][lrow] = w1.x; zdS[lk + 5][lrow] = w1.y; zdS[lk + 6][lrow] = w1.z; zdS[lk + 7][lrow] = w1.w;
    __syncthreads();

    float acc[4][4] = {};
#pragma unroll
    for (int k = 0; k < 32; k++) {
        const float4 a4 = *(const float4*)&zsS[k][ty * 4];
        const float4 b4 = *(const float4*)&zdS[k][tx * 4];
        const float aa[4] = {a4.x, a4.y, a4.z, a4.w};
        const float bb[4] = {b4.x, b4.y, b4.z, b4.w};
#pragma unroll
        for (int i = 0; i < 4; i++)
#pragma unroll
            for (int j = 0; j < 4; j++) acc[i][j] += aa[i] * bb[j];
    }

    float asum = 0.f, s1 = 0.f, s2 = 0.f;
#pragma unroll
    for (int i = 0; i < 4; i++) {
        const int r = r0 + ty * 4 + i;
        const float4 av4 = *(const float4*)&adj[(size_t)r * NND + c0 + tx * 4];
        const float av[4] = {av4.x, av4.y, av4.z, av4.w};
        float* drow = &dec[(size_t)r * NND + c0 + tx * 4];
#pragma unroll
        for (int j = 0; j < 4; j++) {
            float d = acc[i][j];
            drow[j] = d;
            float a = av[j];
            asum += a;
            s1 += a * lsigf(d);
            s2 += (1.f - a) * lsigf(-d);
        }
    }
    __syncthreads();   // done reading zsS/zdS — reuse as reduction buffers
    float* redA = (float*)smem;
    float* redB = redA + 256;
    float* redC = redB + 256;
    redA[tid] = asum; redB[tid] = s1; redC[tid] = s2;
    __syncthreads();
    for (int o = 128; o > 0; o >>= 1) {
        if (tid < o) {
            redA[tid] += redA[tid + o];
            redB[tid] += redB[tid + o];
            redC[tid] += redC[tid + o];
        }
        __syncthreads();
    }
    if (tid == 0) {
        atomicAdd(&acc3[0], (double)redA[0]);
        atomicAdd(&acc3[1], (double)redB[0]);
        atomicAdd(&acc3[2], (double)redC[0]);
    }
}

__global__ __launch_bounds__(256) void fat_kernel(FatArgs fa) {
    extern __shared__ char smem[];
    int bx = blockIdx.x;
    int oi = 0;
    while (oi < fa.nops - 1 && bx >= fa.blk_end[oi]) oi++;
    int lb = bx - (oi ? fa.blk_end[oi - 1] : 0);
    const Op& op = fa.op[oi];
    const int tid = threadIdx.x;
    switch (op.type) {
        case 0: op_gemm(op, lb, tid); break;
        case 1: op_gather(op, fa, lb, tid); break;
        case 2: op_small(op, lb, tid); break;
        case 3: op_gcn(op, fa, lb, tid); break;
        case 4: op_zkld(op, lb, tid); break;
        case 5: op_dec(op, lb, tid, smem); break;
    }
}

// ---------------- finalize ----------------
__global__ void finalize_kernel(const double* __restrict__ accd, float* __restrict__ out) {
    if (threadIdx.x == 0 && blockIdx.x == 0) {
        const double nn2 = (double)NND * (double)NND;
        out[0] = (float)(0.5 * accd[0] / nn2);
        double nll = 0.0;
        for (int t = 0; t < NTS; ++t) {
            double s = accd[1 + 3 * t];
            double S1 = accd[2 + 3 * t];
            double S2 = accd[3 + 3 * t];
            double posw = (nn2 - s) / s;
            double norm = nn2 / ((nn2 - s) * 2.0);
            nll += norm * (-posw * S1 - S2) / nn2;
        }
        out[1] = (float)nll;
    }
}

// ---------------- host ----------------

extern "C" void kernel_launch(void* const* d_in, const int* in_sizes, int n_in,
                              void* d_out, int out_size, void* d_ws, size_t ws_size,
                              hipStream_t stream) {
    (void)in_sizes; (void)n_in; (void)out_size; (void)ws_size;

    const float* x_all = (const float*)d_in[0];
    const int* ei_all = (const int*)d_in[1];
    const float* adj_all = (const float*)d_in[2];
    const float* eps_s_all = (const float*)d_in[3];
    const float* eps_d_all = (const float*)d_in[4];
    const float* phi_x_w = (const float*)d_in[5];
    const float* phi_z_w = (const float*)d_in[6];
    const float* gru_xw0 = (const float*)d_in[7];
    const float* gru_xw1 = (const float*)d_in[8];
    const float* gru_hw = (const float*)d_in[9];
    const float* enc_w = (const float*)d_in[10];
    const float* enc_b = (const float*)d_in[11];
    const float* mean_w = (const float*)d_in[12];
    const float* mean_b = (const float*)d_in[13];
    const float* std_w = (const float*)d_in[14];
    const float* std_b = (const float*)d_in[15];
    const float* pri_w = (const float*)d_in[16];
    const float* pri_b = (const float*)d_in[17];
    const float* pri_mw = (const float*)d_in[18];
    const float* pri_mb = (const float*)d_in[19];
    const float* pri_sw = (const float*)d_in[20];
    const float* pri_sb = (const float*)d_in[21];
    float* out = (float*)d_out;

    size_t off = 0;
    auto alloc = [&](size_t bytes) -> void* {
        void* p = (char*)d_ws + off;
        off = (off + bytes + 255) & ~(size_t)255;
        return p;
    };
    const size_t NH = (size_t)NND * HDI;
    const size_t NH2 = (size_t)NND * H2I;
    const size_t NZ = (size_t)NND * ZDI;

    float* hbase = (float*)alloc(4 * NH * 4);
    u16* h1b = (u16*)alloc(NH * 4);
    u16* nh1b = (u16*)alloc(NH * 4);
    float* phi_x = (float*)alloc(NH * 4);
    float* phi_z = (float*)alloc(NH * 4);
    float* enc_s = (float*)alloc(NH * 4);
    float* enc_d = (float*)alloc(NH * 4);
    float* ginA = (float*)alloc(NH * 4);
    float* ginB = (float*)alloc(NH * 4);
    float* zg = (float*)alloc(NH * 4);
    float* rg = (float*)alloc(NH * 4);
    float* htmp = (float*)alloc(NH * 4);
    u16* cat_b = (u16*)alloc(NH2 * 4);
    u16* xpre_b = (u16*)alloc(NH2 * 4);
    u16* xpre1_b = (u16*)alloc(NH * 4);
    u16* ginA_b = (u16*)alloc(NH * 4);
    u16* ginB_b = (u16*)alloc(NH * 4);
    float* zcat = (float*)alloc((size_t)NND * 64 * 4);
    u16* zcat_b = (u16*)alloc((size_t)NND * 64 * 4);
    u16* xb = (u16*)alloc(XSZ * 4);
    float* xw_s = (float*)alloc(NZ * 4);
    float* xw_d = (float*)alloc(NZ * 4);
    float* mean_s = (float*)alloc(NZ * 4);
    float* mean_d = (float*)alloc(NZ * 4);
    float* std_s = (float*)alloc(NZ * 4);
    float* std_d = (float*)alloc(NZ * 4);
    float* pm_s = (float*)alloc(NZ * 4);
    float* ps_s = (float*)alloc(NZ * 4);
    float* pm_d = (float*)alloc(NZ * 4);
    float* ps_d = (float*)alloc(NZ * 4);
    float* deg = (float*)alloc((size_t)NTS * NND * 4);
    float* dinv = (float*)alloc((size_t)NTS * NND * 4);
    int* counts = (int*)alloc(2 * (size_t)NTS * NND * 4);
    int* cursor = counts + (size_t)NTS * NND;
    int* offsets = (int*)alloc((size_t)NTS * (NND + 1) * 4);
    int* csrc = (int*)alloc((size_t)NTS * NED * 4);
    float* csrw = (float*)alloc((size_t)NTS * NED * 4);
    double* accd = (double*)alloc((1 + 3 * NTS) * 8);

    WtArgs wa;
    int wk[18] = {XDI, 64, H2I, H2I, HDI, HDI, H2I, H2I, H2I, HDI, HDI, HDI,
                  HDI, HDI, HDI, HDI, HDI, HDI};
    const float* wsrc[18] = {
        phi_x_w, phi_z_w,
        enc_w, enc_w + (size_t)H2I * HDI,
        pri_w, pri_w + (size_t)HDI * HDI,
        gru_xw0, gru_xw0 + (size_t)H2I * HDI, gru_xw0 + 2 * (size_t)H2I * HDI,
        gru_xw1, gru_xw1 + (size_t)HDI * HDI, gru_xw1 + 2 * (size_t)HDI * HDI,
        gru_hw, gru_hw + (size_t)HDI * HDI, gru_hw + 2 * (size_t)HDI * HDI,
        gru_hw + 3 * (size_t)HDI * HDI, gru_hw + 4 * (size_t)HDI * HDI,
        gru_hw + 5 * (size_t)HDI * HDI};
    u16* wt[18];
    for (int m = 0; m < 18; m++) {
        wt[m] = (u16*)alloc((size_t)wk[m] * HDI * 4);
        wa.W[m] = wsrc[m];
        wa.Wt[m] = wt[m];
        wa.K[m] = wk[m];
    }

    float* h0 = hbase;
    float* h1 = hbase + NH;
    float* nh0 = hbase + 2 * NH;
    float* nh1 = hbase + 3 * NH;

    hipMemsetAsync(hbase, 0, 2 * NH * 4, stream);
    hipMemsetAsync(h1b, 0, NH * 4, stream);
    hipMemsetAsync(counts, 0, 2 * (size_t)NTS * NND * 4, stream);
    hipMemsetAsync(accd, 0, (1 + 3 * NTS) * 8, stream);

    count_all<<<NTS * NED / 256, 256, 0, stream>>>(ei_all, counts);
    scan_all<<<NTS, 256, 0, stream>>>(counts, offsets, deg, dinv);
    fill_all<<<NTS * NED / 256, 256, 0, stream>>>(ei_all, offsets, cursor, dinv, csrc, csrw);
    wt_transpose<<<dim3(512, 18), 256, 0, stream>>>(wa);
    cvt_x<<<(int)(XSZ / 4 / 256), 256, 0, stream>>>(x_all, xb);

    // ---- fat dispatch builder ----
    FatArgs fa;
    int nb = 0;
    auto beginF = [&](const int* o, const int* cs, const float* cw, const float* dg) {
        fa = FatArgs{};
        fa.offs = o; fa.csrcp = cs; fa.csrwp = cw; fa.degp = dg;
        nb = 0;
    };
    auto addOp = [&](const Op& o, int blocks) {
        fa.op[fa.nops] = o;
        nb += blocks;
        fa.blk_end[fa.nops] = nb;
        fa.nops++;
    };
    auto endF = [&](size_t shm) { fat_kernel<<<nb, 256, shm, stream>>>(fa); };

    auto gemmOp = [&](const u16* A1, int K1, int apl1, const u16* B1a, const u16* B1b,
                      const u16* A2, int K2, int apl2, const u16* B2a, const u16* B2b,
                      const float* b0, const float* b1, float* C0, float* C1, u16* Cb,
                      const float* hg, const float* zgp, int act, int epi, int flags) {
        Op o = {};
        o.type = 0;
        o.a = A1; o.b = A2; o.c = B1a; o.d = B1b; o.e = B2a; o.f = B2b;
        o.g = b0; o.h = b1; o.i = hg; o.j = zgp;
        o.o0 = C0; o.o1 = C1; o.o2 = Cb;
        o.k1 = K1; o.k2 = K2; o.p1 = apl1; o.p2 = apl2;
        o.act = act; o.epi = epi; o.flags = flags;
        return o;
    };
    auto gatherOp = [&](const float* in, void* outp, int ostr, int ooff, int obf, int plane) {
        Op o = {};
        o.type = 1; o.a = in; o.o0 = outp;
        o.k1 = ostr; o.k2 = ooff; o.p1 = obf; o.p2 = plane;
        return o;
    };
    auto smallOp = [&](const float* A, const float* B, const float* bi, float* C, int act) {
        Op o = {};
        o.type = 2; o.a = A; o.b = B; o.c = bi; o.o0 = C; o.act = act;
        return o;
    };
    auto gcnOp = [&](const float* xw, const float* bi, float* C) {
        Op o = {};
        o.type = 3; o.a = xw; o.c = bi; o.o0 = C;
        return o;
    };

    for (int t = 0; t < NTS; ++t) {
        const float* adj_t = adj_all + (size_t)t * NND * NND;
        const float* es_t = eps_s_all + (size_t)t * NND * ZDI;
        const float* ed_t = eps_d_all + (size_t)t * NND * ZDI;
        float* dec_t = out + 2 + (size_t)t * NND * NND;
        const int* off_t = offsets + (size_t)t * (NND + 1);
        const int* csrc_t = csrc + (size_t)t * NED;
        const float* csrw_t = csrw + (size_t)t * NED;
        const float* deg_t = deg + (size_t)t * NND;

        // D1: phi_x GEMM + pri GEMM (both ready at step start)
        beginF(off_t, csrc_t, csrw_t, deg_t);
        addOp(gemmOp(xb + (size_t)t * NND * XDI, XDI, (int)XSZ, wt[0], nullptr,
                     nullptr, 0, 0, nullptr, nullptr, nullptr, nullptr,
                     phi_x, nullptr, nullptr, nullptr, nullptr, 1, 0, 0), 512);
        addOp(gemmOp(h1b, HDI, (int)NH, wt[4], wt[5], nullptr, 0, 0, nullptr, nullptr,
                     pri_b, pri_b + HDI, zg, rg, nullptr, nullptr, nullptr, 1, 0, 1 | 2), 1024);
        endF(0);

        // D2: gather cat (2 segs) + 4 pri smalls
        beginF(off_t, csrc_t, csrw_t, deg_t);
        addOp(gatherOp(phi_x, cat_b, H2I, 0, 1, (int)NH2), 512);
        addOp(gatherOp(h1, cat_b, H2I, HDI, 1, (int)NH2), 512);
        addOp(smallOp(zg, pri_mw, pri_mb, pm_s, 0), 256);
        addOp(smallOp(zg, pri_sw, pri_sb, ps_s, 4), 256);
        addOp(smallOp(rg, pri_mw + (size_t)HDI * ZDI, pri_mb + ZDI, pm_d, 0), 256);
        addOp(smallOp(rg, pri_sw + (size_t)HDI * ZDI, pri_sb + ZDI, ps_d, 4), 256);
        endF(0);

        // D3: enc GEMM (two-out)
        beginF(off_t, csrc_t, csrw_t, deg_t);
        addOp(gemmOp(cat_b, H2I, (int)NH2, wt[2], wt[3], nullptr, 0, 0, nullptr, nullptr,
                     enc_b, enc_b + HDI, enc_s, enc_d, nullptr, nullptr, nullptr, 1, 0, 1 | 2), 1024);
        endF(0);

        // D4: small xw_s/xw_d + gather gin(enc_s)/gin(enc_d) fp32
        beginF(off_t, csrc_t, csrw_t, deg_t);
        addOp(smallOp(enc_s, mean_w, nullptr, xw_s, 0), 256);
        addOp(smallOp(enc_d, mean_w + (size_t)HDI * ZDI, nullptr, xw_d, 0), 256);
        addOp(gatherOp(enc_s, ginA, HDI, 0, 0, 0), 512);
        addOp(gatherOp(enc_d, ginB, HDI, 0, 0, 0), 512);
        endF(0);

        // D5: gcn pair + std smalls
        beginF(off_t, csrc_t, csrw_t, deg_t);
        addOp(gcnOp(xw_s, mean_b, mean_s), 256);
        addOp(gcnOp(xw_d, mean_b + ZDI, mean_d), 256);
        addOp(smallOp(ginA, std_w, std_b, std_s, 4), 256);
        addOp(smallOp(ginB, std_w + (size_t)HDI * ZDI, std_b + ZDI, std_d, 4), 256);
        endF(0);

        // D6: zkld
        beginF(off_t, csrc_t, csrw_t, deg_t);
        {
            Op o = {};
            o.type = 4;
            o.a = mean_s; o.b = std_s; o.c = es_t; o.d = mean_d; o.e = std_d; o.f = ed_t;
            o.g = pm_s; o.h = ps_s; o.i = pm_d; o.j = ps_d;
            o.o0 = zcat; o.o1 = zcat_b; o.o2 = &accd[0];
            addOp(o, 256);
        }
        endF(0);

        // D7: phi_z GEMM + dec_bce
        beginF(off_t, csrc_t, csrw_t, deg_t);
        addOp(gemmOp(zcat_b, 64, ZPL, wt[1], nullptr, nullptr, 0, 0, nullptr, nullptr,
                     nullptr, nullptr, phi_z, nullptr, nullptr, nullptr, nullptr, 1, 0, 0), 512);
        {
            Op o = {};
            o.type = 5;
            o.a = zcat; o.b = adj_t; o.o0 = dec_t; o.o1 = &accd[1 + 3 * t];
            addOp(o, 1024);
        }
        endF(32 * 68 * 4 * 2);

        // D8: gather xpre (phi_x, phi_z) + gin(h0)
        beginF(off_t, csrc_t, csrw_t, deg_t);
        addOp(gatherOp(phi_x, xpre_b, H2I, 0, 1, (int)NH2), 512);
        addOp(gatherOp(phi_z, xpre_b, H2I, HDI, 1, (int)NH2), 512);
        addOp(gatherOp(h0, ginA_b, HDI, 0, 1, (int)NH), 512);
        endF(0);

        // D9: GRU0 z/r GEMM
        beginF(off_t, csrc_t, csrw_t, deg_t);
        addOp(gemmOp(xpre_b, H2I, (int)NH2, wt[6], wt[7], ginA_b, HDI, (int)NH, wt[12], wt[13],
                     nullptr, nullptr, zg, htmp, nullptr, h0, nullptr, 2, 1, 1 | 4), 1024);
        endF(0);

        // D10: gather gin(htmp)
        beginF(off_t, csrc_t, csrw_t, deg_t);
        addOp(gatherOp(htmp, ginB_b, HDI, 0, 1, (int)NH), 512);
        endF(0);

        // D11: nh0 GEMM (EPI2)
        beginF(off_t, csrc_t, csrw_t, deg_t);
        addOp(gemmOp(xpre_b, H2I, (int)NH2, wt[8], nullptr, ginB_b, HDI, (int)NH, wt[14], nullptr,
                     nullptr, nullptr, nh0, nullptr, nullptr, h0, zg, 0, 2, 4), 512);
        endF(0);

        // D12: gather gin(nh0) + gin(h1)
        beginF(off_t, csrc_t, csrw_t, deg_t);
        addOp(gatherOp(nh0, xpre1_b, HDI, 0, 1, (int)NH), 512);
        addOp(gatherOp(h1, ginA_b, HDI, 0, 1, (int)NH), 512);
        endF(0);

        // D13: GRU1 z/r GEMM
        beginF(off_t, csrc_t, csrw_t, deg_t);
        addOp(gemmOp(xpre1_b, HDI, (int)NH, wt[9], wt[10], ginA_b, HDI, (int)NH, wt[15], wt[16],
                     nullptr, nullptr, zg, htmp, nullptr, h1, nullptr, 2, 1, 1 | 4), 1024);
        endF(0);

        // D14: gather gin(htmp)
        beginF(off_t, csrc_t, csrw_t, deg_t);
        addOp(gatherOp(htmp, ginB_b, HDI, 0, 1, (int)NH), 512);
        endF(0);

        // D15: nh1 GEMM (EPI2 + bf16 copy)
        beginF(off_t, csrc_t, csrw_t, deg_t);
        addOp(gemmOp(xpre1_b, HDI, (int)NH, wt[11], nullptr, ginB_b, HDI, (int)NH, wt[17], nullptr,
                     nullptr, nullptr, nh1, nullptr, nh1b, h1, zg, 0, 2, 4 | 8), 512);
        endF(0);

        // swap ping-pong
        float* tp;
        tp = h0; h0 = nh0; nh0 = tp;
        tp = h1; h1 = nh1; nh1 = tp;
        u16* tb = h1b; h1b = nh1b; nh1b = tb;
    }

    finalize_kernel<<<1, 64, 0, stream>>>(accd, out);
}